// Round 11
// baseline (446.588 us; speedup 1.0000x reference)
//
#include <hip/hip_runtime.h>

typedef unsigned short u16;
typedef unsigned int u32;
typedef unsigned long long u64;

typedef __bf16 bf16x8 __attribute__((ext_vector_type(8)));
typedef float f32x4 __attribute__((ext_vector_type(4)));
typedef float f32x16 __attribute__((ext_vector_type(16)));

__device__ __forceinline__ float b2f(u16 u) {
    union { u32 i; float f; } c; c.i = ((u32)u) << 16; return c.f;
}
__device__ __forceinline__ u16 f2b(float f) {
    union { float f; u32 i; } c; c.f = f;
    u32 r = c.i + 0x7fffu + ((c.i >> 16) & 1u);
    return (u16)(r >> 16);
}
__device__ __forceinline__ u32 pack2(float a, float b) {
    return (u32)f2b(a) | ((u32)f2b(b) << 16);
}
__device__ __forceinline__ u32 cvt_pk_bf16(float a, float b) {
    u32 r;
    asm("v_cvt_pk_bf16_f32 %0, %1, %2" : "=v"(r) : "v"(a), "v"(b));
    return r;
}
__device__ __forceinline__ float fexp2(float x) {
    float r;
    asm("v_exp_f32 %0, %1" : "=v"(r) : "v"(x));
    return r;
}

__device__ __forceinline__ f32x4 mfma16(bf16x8 a, bf16x8 b, f32x4 c) {
    return __builtin_amdgcn_mfma_f32_16x16x32_bf16(a, b, c, 0, 0, 0);
}
__device__ __forceinline__ f32x16 mfma32(bf16x8 a, bf16x8 b, f32x16 c) {
    return __builtin_amdgcn_mfma_f32_32x32x16_bf16(a, b, c, 0, 0, 0);
}

__device__ __forceinline__ void lds_cp16(const u16* gsrc, u16* ldst) {
    __builtin_amdgcn_global_load_lds(
        (const __attribute__((address_space(1))) u32*)gsrc,
        (__attribute__((address_space(3))) u32*)ldst, 16, 0, 0);
}

struct ConvJobs {
    const float* s[4];    // wq, wk, wv, wo  [640][640]
    const float* up[4];   // q_up, ...       [640][4]
    const float* dn[4];   // q_down, ...     [4][640]
    u16* d[4];
};

// ---------------------------------------------------------------------------
// Device-scope grid barrier: monotone counter (reset by host memset each
// launch). Safe: grid=256 blocks, LDS 51712B -> >=2 blocks/CU capacity ->
// all 256 blocks resident under any placement.
// ---------------------------------------------------------------------------
__device__ __forceinline__ void gridbar(u32* cnt, int idx) {
    __syncthreads();
    __threadfence();
    if (threadIdx.x == 0) {
        atomicAdd(&cnt[idx], 1u);
        while (atomicAdd(&cnt[idx], 0u) < 256u) __builtin_amdgcn_s_sleep(2);
    }
    __syncthreads();
    __threadfence();
}

// ---------------------------------------------------------------------------
// 512-thread (8-wave) 128x128 GEMM tile, pipelined K-loop (3 LDS buf,
// 2-deep prefetch, counted vmcnt(2)). Wave w: wm=(w&1)*64, wn=(w>>1)*32,
// acc[4][2]. Math order identical to the 256-thread version.
// mode 0: bf16 [B,H,S,80] scaled; 1: fp32 [M,640]+bias; 2: V^T key-permuted.
// ---------------------------------------------------------------------------
__device__ __forceinline__ void gemm_tile512(const u16* __restrict__ Ap,
                                             const u16* __restrict__ W,
                                             void* outp, float scl, int md,
                                             const float* __restrict__ bias,
                                             int m0, int n0, u16* smem) {
    int tid = threadIdx.x, lane = tid & 63, wid = tid >> 6;
    int g = lane >> 4, l15 = lane & 15;
    u16* As_ = smem;             // 3 x 4096 u16
    u16* Bs_ = smem + 12288;     // 3 x 4096 u16
    f32x4 acc[4][2] = {};
    int wm = (wid & 1) * 64, wn = (wid >> 1) * 32;

    int r0 = tid >> 2, cb = (tid & 3) * 8;
    const u16* pA = Ap + (size_t)(m0 + r0) * 640 + cb;
    const u16* pB = W + (size_t)(n0 + r0) * 640 + cb;

    __syncthreads();   // prior tile/phase done with LDS before we overwrite

    auto stage = [&](int buf, int k0) {
        lds_cp16(pA + k0, As_ + buf * 4096 + tid * 8);
        lds_cp16(pB + k0, Bs_ + buf * 4096 + tid * 8);
    };
    auto compute = [&](int cur) {
        const u16* as = As_ + cur * 4096;
        const u16* bs = Bs_ + cur * 4096;
        bf16x8 af[4], bfv[2];
#pragma unroll
        for (int i = 0; i < 4; ++i)
            af[i] = *(const bf16x8*)(as + (wm + i * 16 + l15) * 32 + g * 8);
#pragma unroll
        for (int j = 0; j < 2; ++j)
            bfv[j] = *(const bf16x8*)(bs + (wn + j * 16 + l15) * 32 + g * 8);
#pragma unroll
        for (int i = 0; i < 4; ++i)
#pragma unroll
            for (int j = 0; j < 2; ++j)
                acc[i][j] = mfma16(af[i], bfv[j], acc[i][j]);
    };

    stage(0, 0);
    stage(1, 32);          // 4 loads/thread outstanding
    int cur = 0;
    for (int t = 0; t < 19; ++t) {
        asm volatile("s_waitcnt vmcnt(2)" ::: "memory");
        __builtin_amdgcn_s_barrier();
        asm volatile("" ::: "memory");
        if (t < 18) stage((cur == 0) ? 2 : cur - 1, (t + 2) * 32);
        compute(cur);
        cur = (cur == 2) ? 0 : cur + 1;
    }
    asm volatile("s_waitcnt vmcnt(0)" ::: "memory");
    __builtin_amdgcn_s_barrier();
    asm volatile("" ::: "memory");
    compute(cur);

    if (md == 2) {
        // V^T epilogue: LDS transpose then coalesced row stores
        __syncthreads();
        u16* Tl = smem;    // [128 n][136 m] u16
#pragma unroll
        for (int i = 0; i < 4; ++i) {
#pragma unroll
            for (int j = 0; j < 2; ++j) {
                uint2 pk;
                pk.x = pack2(acc[i][j][0], acc[i][j][1]);
                pk.y = pack2(acc[i][j][2], acc[i][j][3]);
                *(uint2*)(Tl + (wn + j * 16 + l15) * 136 + wm + i * 16 + g * 4) = pk;
            }
        }
        __syncthreads();
        int bb2 = m0 >> 11;
        int sl0 = m0 & 2047;
        u16* outb_ = (u16*)outp;
#pragma unroll
        for (int it = 0; it < 8; ++it) {
            int qq = it * 512 + tid;        // 0..4095 quads
            int row = qq >> 5;              // n_local
            int pos = (qq & 31) * 4;        // output position
            int ss = (pos & ~12) | ((pos & 4) << 1) | ((pos & 8) >> 1);
            uint2 val = *(const uint2*)(Tl + row * 136 + ss);
            int n = n0 + row;
            int h = n / 80, d = n - h * 80;
            *(uint2*)(outb_ + (((size_t)bb2 * 8 + h) * 96 + d) * 2048 + sl0 + pos) = val;
        }
        __syncthreads();
        return;
    }

    float bv[2];
#pragma unroll
    for (int j = 0; j < 2; ++j)
        bv[j] = (md == 1) ? bias[n0 + wn + j * 16 + l15] : 0.f;
    float* outf = (float*)outp;
    u16* outb = (u16*)outp;
#pragma unroll
    for (int i = 0; i < 4; ++i) {
#pragma unroll
        for (int r = 0; r < 4; ++r) {
            int m = m0 + wm + i * 16 + g * 4 + r;
#pragma unroll
            for (int j = 0; j < 2; ++j) {
                int n = n0 + wn + j * 16 + l15;
                float v = acc[i][j][r] + bv[j];
                if (md == 1) {
                    outf[(size_t)m * 640 + n] = v;
                } else {
                    int bb = m >> 11, s = m & 2047;
                    int h = n / 80, d = n - h * 80;
                    outb[(((size_t)bb * 8 + h) * 2048 + s) * 80 + d] = f2b(v * scl);
                }
            }
        }
    }
}

// ---------------------------------------------------------------------------
// Flash attention body (R10-proven), device-function form.
// ---------------------------------------------------------------------------
__device__ __forceinline__ void flash512(int bid, const u16* __restrict__ Q,
                                         const u16* __restrict__ K,
                                         const u16* __restrict__ Vt_g,
                                         u16* __restrict__ O, u16* lds) {
    int q0 = (bid & 7) * 256;
    int bh = bid >> 3;
    int tid = threadIdx.x;
    int lane = tid & 63, wid = tid >> 6, l31 = lane & 31, h2 = lane >> 5;
    const size_t base = (size_t)bh * 2048 * 80;
    const size_t vbase = (size_t)bh * 96 * 2048;

    u16* Ks0 = lds;
    u16* Vt0 = lds + 11264;

    bf16x8 qf[5];
    {
        int qrow = q0 + wid * 32 + l31;
#pragma unroll
        for (int ks = 0; ks < 5; ++ks)
            qf[ks] = *(const bf16x8*)(Q + base + (size_t)qrow * 80 + ks * 16 + h2 * 8);
    }

    f32x16 oa[3] = {};
    const float C2 = 17.312340490667562f;

    auto stage = [&](int buf, int kt) {
#pragma unroll
        for (int it = 0; it < 4; ++it) {
            int c = tid + it * 512;
            if (c < 704) {
                int row = c / 11, col = c - row * 11;
                lds_cp16(K + base + (size_t)(kt + row) * 80 + col * 8,
                         Ks0 + buf * 5632 + c * 8);
            } else if (c < 1600) {
                int t = c - 704;
                int row = t / 9, col = t - row * 9;
                lds_cp16(Vt_g + vbase + (size_t)row * 2048 + kt + col * 8,
                         Vt0 + buf * 7200 + t * 8);
            }
        }
    };

    stage(0, 0);
    __syncthreads();

    for (int i = 0; i < 32; ++i) {
        int cur = i & 1;
        if (i < 31) stage(cur ^ 1, (i + 1) * 64);

        const u16* ks = Ks0 + cur * 5632;
        const u16* vt = Vt0 + cur * 7200;

#pragma unroll
        for (int kk2 = 0; kk2 < 2; ++kk2) {
            f32x16 s = {};
            __builtin_amdgcn_s_setprio(1);
#pragma unroll
            for (int ks5 = 0; ks5 < 5; ++ks5) {
                bf16x8 kf = *(const bf16x8*)(ks + (kk2 * 32 + l31) * 88 + ks5 * 16 + h2 * 8);
                s = mfma32(kf, qf[ks5], s);
            }
            __builtin_amdgcn_s_setprio(0);
            u32 d[8];
#pragma unroll
            for (int j = 0; j < 8; ++j)
                d[j] = cvt_pk_bf16(fexp2(s[2 * j] - C2), fexp2(s[2 * j + 1] - C2));
            __builtin_amdgcn_s_setprio(1);
#pragma unroll
            for (int sl = 0; sl < 2; ++sl) {
                union { u32 w[4]; bf16x8 v; } pa;
                pa.w[0] = d[4 * sl + 0];
                pa.w[1] = d[4 * sl + 1];
                pa.w[2] = d[4 * sl + 2];
                pa.w[3] = d[4 * sl + 3];
#pragma unroll
                for (int nt = 0; nt < 3; ++nt) {
                    bf16x8 vf = *(const bf16x8*)(vt + (nt * 32 + l31) * 72 +
                                                 kk2 * 32 + sl * 16 + h2 * 8);
                    oa[nt] = mfma32(pa.v, vf, oa[nt]);
                }
            }
            __builtin_amdgcn_s_setprio(0);
        }
        __syncthreads();
    }

    int b = bh >> 3, h = bh & 7;
    float inv[16];
#pragma unroll
    for (int reg = 0; reg < 16; ++reg)
        inv[reg] = 1.f / __shfl(oa[2][reg], (lane & 32) + 16, 64);
#pragma unroll
    for (int nt = 0; nt < 3; ++nt) {
        int vd = nt * 32 + l31;
        if (vd < 80) {
#pragma unroll
            for (int reg = 0; reg < 16; ++reg) {
                int q = q0 + wid * 32 + (reg & 3) + 8 * (reg >> 2) + 4 * h2;
                O[((size_t)(b * 2048 + q)) * 640 + h * 80 + vd] = f2b(oa[nt][reg] * inv[reg]);
            }
        }
    }
}

// ---------------------------------------------------------------------------
// FUSED persistent kernel: prep -> [bar] -> QKV gemm -> [bar] -> flash ->
// [bar] -> O gemm. grid 256 x 512.
// ---------------------------------------------------------------------------
struct FusedArgs {
    ConvJobs cj;
    const float* x;
    u16* xb;
    u16* vt;
    u16* q_ws;
    u16* k_ws;
    u16* attn;
    const float* bias;
    float* out;
    u32* cnt;
};

__global__ __launch_bounds__(512) void fused(FusedArgs A) {
    __shared__ __align__(16) u16 smem[25856];   // 51712 B (flash needs 51328)
    int bid = blockIdx.x, tid = threadIdx.x;

    // ---- phase 0: LoRA-folded weight convert + x convert + V^T pads ----
    {
        const int WE = 409600;            // weight float4 units
        const int XE = WE + 1310720;      // + x float4 units
        const int PE = XE + 262144;       // + pad ushort4 units
        for (int u = bid * 512 + tid; u < PE; u += 131072) {
            if (u < WE) {
                int j = u / 102400;
                int i = u - j * 102400;
                int n = i / 160;
                int k4 = (i - n * 160) * 4;
                float4 w = ((const float4*)A.cj.s[j])[i];
                float4 uu = *(const float4*)(A.cj.up[j] + n * 4);
                const float* dnp = A.cj.dn[j];
                float4 d0 = *(const float4*)(dnp + k4);
                float4 d1 = *(const float4*)(dnp + 640 + k4);
                float4 d2 = *(const float4*)(dnp + 1280 + k4);
                float4 d3 = *(const float4*)(dnp + 1920 + k4);
                ushort4 o;
                o.x = f2b(w.x + uu.x * d0.x + uu.y * d1.x + uu.z * d2.x + uu.w * d3.x);
                o.y = f2b(w.y + uu.x * d0.y + uu.y * d1.y + uu.z * d2.y + uu.w * d3.y);
                o.z = f2b(w.z + uu.x * d0.z + uu.y * d1.z + uu.z * d2.z + uu.w * d3.z);
                o.w = f2b(w.w + uu.x * d0.w + uu.y * d1.w + uu.z * d2.w + uu.w * d3.w);
                ((ushort4*)A.cj.d[j])[i] = o;
            } else if (u < XE) {
                int i = u - WE;
                float4 v = ((const float4*)A.x)[i];
                ushort4 o;
                o.x = f2b(v.x); o.y = f2b(v.y); o.z = f2b(v.z); o.w = f2b(v.w);
                ((ushort4*)A.xb)[i] = o;
            } else {
                int idx = u - XE;
                int q = idx * 4;
                int bh = q >> 15;
                int rem = q & 32767;
                int row = rem >> 11, col = rem & 2047;
                u16 val = (row == 0) ? (u16)0x3F80 : (u16)0;
                ushort4 o = make_ushort4(val, val, val, val);
                *(ushort4*)(A.vt + ((size_t)bh * 96 + 80 + row) * 2048 + col) = o;
            }
        }
    }
    gridbar(A.cnt, 0);

    // ---- phase 1: QKV projections (LoRA folded; V direct-transposed) ----
    const float qscale = 0.11180339887498949f * 1.4426950408889634f;
    for (int t = bid; t < 960; t += 256) {
        int xm = t & 63;
        int r = t >> 6;
        int yn = r % 5, z = r / 5;
        const u16* Wz = (z == 0) ? (const u16*)A.cj.d[0]
                      : (z == 1) ? (const u16*)A.cj.d[1] : (const u16*)A.cj.d[2];
        void* oz = (z == 0) ? (void*)A.q_ws : (z == 1) ? (void*)A.k_ws : (void*)A.vt;
        float sz = (z == 0) ? qscale : 1.f;
        int mz = (z == 2) ? 2 : 0;
        gemm_tile512(A.xb, Wz, oz, sz, mz, A.bias, xm * 128, yn * 128, smem);
    }
    gridbar(A.cnt, 1);

    // ---- phase 2: flash attention ----
    flash512(bid, A.q_ws, A.k_ws, A.vt, A.attn, smem);
    gridbar(A.cnt, 2);

    // ---- phase 3: O projection (+bias) ----
    for (int t = bid; t < 320; t += 256) {
        int xm = t & 63, yn = t >> 6;
        gemm_tile512(A.attn, (const u16*)A.cj.d[3], A.out, 1.f, 1, A.bias,
                     xm * 128, yn * 128, smem);
    }
}

// ===========================================================================
// FALLBACK path (R10-proven 4-kernel pipeline) — used when ws too small.
// ===========================================================================
__global__ __launch_bounds__(256) void prep4(ConvJobs J,
                                             const float* __restrict__ x,
                                             u16* __restrict__ xb,
                                             u16* __restrict__ vt, int do_pad) {
    int bx = blockIdx.x;
    if (bx < 1600) {
        int j = bx / 400;
        int i = (bx - j * 400) * 256 + threadIdx.x;
        int n = i / 160;
        int k4 = (i - n * 160) * 4;
        float4 w = ((const float4*)J.s[j])[i];
        float4 u = *(const float4*)(J.up[j] + n * 4);
        const float* dnp = J.dn[j];
        float4 d0 = *(const float4*)(dnp + k4);
        float4 d1 = *(const float4*)(dnp + 640 + k4);
        float4 d2 = *(const float4*)(dnp + 1280 + k4);
        float4 d3 = *(const float4*)(dnp + 1920 + k4);
        ushort4 o;
        o.x = f2b(w.x + u.x * d0.x + u.y * d1.x + u.z * d2.x + u.w * d3.x);
        o.y = f2b(w.y + u.x * d0.y + u.y * d1.y + u.z * d2.y + u.w * d3.y);
        o.z = f2b(w.z + u.x * d0.z + u.y * d1.z + u.z * d2.z + u.w * d3.z);
        o.w = f2b(w.w + u.x * d0.w + u.y * d1.w + u.z * d2.w + u.w * d3.w);
        ((ushort4*)J.d[j])[i] = o;
    } else if (bx < 2880) {
        int base = (bx - 1600) * 1024 + threadIdx.x;
#pragma unroll
        for (int it = 0; it < 4; ++it) {
            int i = base + it * 256;
            float4 v = ((const float4*)x)[i];
            ushort4 o;
            o.x = f2b(v.x); o.y = f2b(v.y); o.z = f2b(v.z); o.w = f2b(v.w);
            ((ushort4*)xb)[i] = o;
        }
    } else if (do_pad) {
        int idx = (bx - 2880) * 256 + threadIdx.x;
        int q = idx * 4;
        int bh = q >> 15;
        int rem = q & 32767;
        int row = rem >> 11, col = rem & 2047;
        u16 val = (row == 0) ? (u16)0x3F80 : (u16)0;
        ushort4 o = make_ushort4(val, val, val, val);
        *(ushort4*)(vt + ((size_t)bh * 96 + 80 + row) * 2048 + col) = o;
    }
}

struct QkvPtrs {
    const u16* W[3];
    void* out[3];
    float scale[3];
    int mode[3];
};

__global__ __launch_bounds__(256) void gemm_bt(const u16* __restrict__ A, QkvPtrs P,
                                               const float* __restrict__ bias) {
    int z = blockIdx.z;
    const u16* W = P.W[z];
    const float scl = P.scale[z];
    const int md = P.mode[z];
    int m0 = blockIdx.x * 128, n0 = blockIdx.y * 128;
    int tid = threadIdx.x, lane = tid & 63, wid = tid >> 6;
    int g = lane >> 4, l15 = lane & 15;
    __shared__ __align__(16) u16 smem[24576];
    u16* As_ = smem;
    u16* Bs_ = smem + 12288;
    f32x4 acc[4][4] = {};
    int wm = (wid & 1) * 64, wn = (wid >> 1) * 64;

    int r0 = tid >> 2, cb = (tid & 3) * 8;
    const u16* pA = A + (size_t)(m0 + r0) * 640 + cb;
    const u16* pB = W + (size_t)(n0 + r0) * 640 + cb;

    auto stage = [&](int buf, int k0) {
        u16* da = As_ + buf * 4096 + tid * 8;
        u16* db = Bs_ + buf * 4096 + tid * 8;
        lds_cp16(pA + k0, da);
        lds_cp16(pA + 40960 + k0, da + 2048);
        lds_cp16(pB + k0, db);
        lds_cp16(pB + 40960 + k0, db + 2048);
    };
    auto compute = [&](int cur) {
        const u16* as = As_ + cur * 4096;
        const u16* bs = Bs_ + cur * 4096;
        bf16x8 af[4], bfv[4];
#pragma unroll
        for (int q4 = 0; q4 < 4; ++q4) {
            af[q4]  = *(const bf16x8*)(as + (wm + q4 * 16 + l15) * 32 + g * 8);
            bfv[q4] = *(const bf16x8*)(bs + (wn + q4 * 16 + l15) * 32 + g * 8);
        }
#pragma unroll
        for (int i = 0; i < 4; ++i)
#pragma unroll
            for (int j = 0; j < 4; ++j)
                acc[i][j] = mfma16(af[i], bfv[j], acc[i][j]);
    };

    stage(0, 0);
    stage(1, 32);
    int cur = 0;
    for (int t = 0; t < 19; ++t) {
        asm volatile("s_waitcnt vmcnt(4)" ::: "memory");
        __builtin_amdgcn_s_barrier();
        asm volatile("" ::: "memory");
        if (t < 18) stage((cur == 0) ? 2 : cur - 1, (t + 2) * 32);
        compute(cur);
        cur = (cur == 2) ? 0 : cur + 1;
    }
    asm volatile("s_waitcnt vmcnt(0)" ::: "memory");
    __builtin_amdgcn_s_barrier();
    asm volatile("" ::: "memory");
    compute(cur);

    float bv[4];
#pragma unroll
    for (int j = 0; j < 4; ++j)
        bv[j] = (md == 1) ? bias[n0 + wn + j * 16 + l15] : 0.f;

    if (md == 2) {
        __syncthreads();
        u16* Tl = smem;
#pragma unroll
        for (int i = 0; i < 4; ++i) {
#pragma unroll
            for (int j = 0; j < 4; ++j) {
                uint2 pk;
                pk.x = pack2(acc[i][j][0], acc[i][j][1]);
                pk.y = pack2(acc[i][j][2], acc[i][j][3]);
                *(uint2*)(Tl + (wn + j * 16 + l15) * 136 + wm + i * 16 + g * 4) = pk;
            }
        }
        __syncthreads();
        int bb2 = m0 >> 11;
        int sl0 = m0 & 2047;
        u16* outb_ = (u16*)P.out[z];
#pragma unroll
        for (int it = 0; it < 16; ++it) {
            int qq = it * 256 + tid;
            int row = qq >> 5;
            int pos = (qq & 31) * 4;
            int ss = (pos & ~12) | ((pos & 4) << 1) | ((pos & 8) >> 1);
            uint2 val = *(const uint2*)(Tl + row * 136 + ss);
            int n = n0 + row;
            int h = n / 80, d = n - h * 80;
            *(uint2*)(outb_ + (((size_t)bb2 * 8 + h) * 96 + d) * 2048 + sl0 + pos) = val;
        }
        return;
    }

    float* outf = (float*)P.out[z];
    u16* outb = (u16*)P.out[z];
#pragma unroll
    for (int i = 0; i < 4; ++i) {
#pragma unroll
        for (int r = 0; r < 4; ++r) {
            int m = m0 + wm + i * 16 + g * 4 + r;
#pragma unroll
            for (int j = 0; j < 4; ++j) {
                int n = n0 + wn + j * 16 + l15;
                float v = acc[i][j][r] + bv[j];
                if (md == 1) {
                    outf[(size_t)m * 640 + n] = v;
                } else {
                    int bb = m >> 11, s = m & 2047;
                    int h = n / 80, d = n - h * 80;
                    outb[(((size_t)bb * 8 + h) * 2048 + s) * 80 + d] = f2b(v * scl);
                }
            }
        }
    }
}

__global__ __launch_bounds__(256) void transpose_v(const u16* __restrict__ Vin,
                                                   u16* __restrict__ Vout) {
    __shared__ u32 lds32[64 * 41];
    int bh = blockIdx.y;
    int s0 = blockIdx.x * 64;
    int tid = threadIdx.x;
    const u16* in = Vin + (size_t)bh * 2048 * 80;
    u16* out = Vout + (size_t)bh * 96 * 2048;

    for (int t = tid; t < 640; t += 256) {
        int s = t / 10, c = t - s * 10;
        uint4 v = *(const uint4*)(in + (size_t)(s0 + s) * 80 + c * 8);
        u32* p = lds32 + s * 41 + c * 4;
        p[0] = v.x; p[1] = v.y; p[2] = v.z; p[3] = v.w;
    }
    __syncthreads();
    for (int t = tid; t < 640; t += 256) {
        int d = t >> 3, c8 = t & 7;
        int dp = d >> 1, hi = d & 1;
        u16 vals[8];
#pragma unroll
        for (int j = 0; j < 8; ++j) {
            u32 w = lds32[(c8 * 8 + j) * 41 + dp];
            vals[j] = hi ? (u16)(w >> 16) : (u16)(w & 0xffff);
        }
        u16* dst = out + (size_t)d * 2048 + s0 + (c8 >> 1) * 16 + (c8 & 1) * 4;
        *(uint2*)dst = *(const uint2*)(vals);
        *(uint2*)(dst + 8) = *(const uint2*)(vals + 4);
    }
    for (int t = tid; t < 1024; t += 256) {
        int r = t >> 6, c = t & 63;
        out[(size_t)(80 + r) * 2048 + s0 + c] = (r == 0) ? 0x3F80 : 0;
    }
}

__global__ __launch_bounds__(512) void flash_attn(const u16* __restrict__ Q,
                                                  const u16* __restrict__ K,
                                                  const u16* __restrict__ Vt_g,
                                                  u16* __restrict__ O) {
    __shared__ __align__(16) u16 lds[2 * 5632 + 2 * 7200];
    int bid = blockIdx.x + blockIdx.y * 8;
    flash512(((bid & 255) & 7) | ((bid >> 3) << 3) ? bid : bid, Q, K, Vt_g, O, lds);
}

// ---------------------------------------------------------------------------
extern "C" void kernel_launch(void* const* d_in, const int* in_sizes, int n_in,
                              void* d_out, int out_size, void* d_ws, size_t ws_size,
                              hipStream_t stream) {
    const float* x      = (const float*)d_in[0];
    const float* wq     = (const float*)d_in[1];
    const float* wk     = (const float*)d_in[2];
    const float* wv     = (const float*)d_in[3];
    const float* wo     = (const float*)d_in[4];
    const float* bo     = (const float*)d_in[5];
    const float* q_down = (const float*)d_in[6];
    const float* q_up   = (const float*)d_in[7];
    const float* k_down = (const float*)d_in[8];
    const float* k_up   = (const float*)d_in[9];
    const float* v_down = (const float*)d_in[10];
    const float* v_up   = (const float*)d_in[11];
    const float* o_down = (const float*)d_in[12];
    const float* o_up   = (const float*)d_in[13];

    char* ws = (char*)d_ws;
    u16* xb    = (u16*)(ws);
    u16* wbv   = (u16*)(ws + 10485760);
    u16* wbq   = (u16*)(ws + 11304960);
    u16* wbk   = (u16*)(ws + 12124160);
    u16* wbo   = (u16*)(ws + 12943360);
    u16* q_ws  = (u16*)(ws + 13762560);
    u16* k_ws  = (u16*)(ws + 24248320);
    u16* v_ws  = (u16*)(ws + 34734080);
    u16* attn  = (u16*)(ws + 45219840);

    const size_t vt_off = 56360960;
    const size_t vt_end = vt_off + 12582912 + 16384;   // incl. staging slack
    const size_t cnt_off = vt_end;                      // 64 B of counters
    const bool fused_ok = (ws_size >= cnt_off + 64);
    const bool direct_vt = (ws_size >= vt_end);
    u16* vT_ws = direct_vt ? (u16*)(ws + vt_off) : (u16*)(ws);

    ConvJobs cj;
    cj.s[0] = wq; cj.up[0] = q_up; cj.dn[0] = q_down; cj.d[0] = wbq;
    cj.s[1] = wk; cj.up[1] = k_up; cj.dn[1] = k_down; cj.d[1] = wbk;
    cj.s[2] = wv; cj.up[2] = v_up; cj.dn[2] = v_down; cj.d[2] = wbv;
    cj.s[3] = wo; cj.up[3] = o_up; cj.dn[3] = o_down; cj.d[3] = wbo;

    if (fused_ok) {
        u32* cnt = (u32*)(ws + cnt_off);
        hipMemsetAsync(cnt, 0, 64, stream);
        FusedArgs fa;
        fa.cj = cj;
        fa.x = x; fa.xb = xb; fa.vt = vT_ws;
        fa.q_ws = q_ws; fa.k_ws = k_ws; fa.attn = attn;
        fa.bias = bo; fa.out = (float*)d_out; fa.cnt = cnt;
        fused<<<256, 512, 0, stream>>>(fa);
        return;
    }

    // --------- fallback: R10 4-kernel pipeline ---------
    prep4<<<3904, 256, 0, stream>>>(cj, x, xb, vT_ws, direct_vt ? 1 : 0);

    QkvPtrs pq;
    pq.W[0] = wbq; pq.W[1] = wbk; pq.W[2] = wbv;
    pq.out[0] = q_ws; pq.out[1] = k_ws;
    pq.out[2] = direct_vt ? (void*)vT_ws : (void*)v_ws;
    pq.scale[0] = 0.11180339887498949f * 1.4426950408889634f;
    pq.scale[1] = 1.0f;
    pq.scale[2] = 1.0f;
    pq.mode[0] = 0; pq.mode[1] = 0; pq.mode[2] = direct_vt ? 2 : 0;
    gemm_bt<<<dim3(64, 5, 3), 256, 0, stream>>>(xb, pq, bo);

    if (!direct_vt)
        transpose_v<<<dim3(32, 32), 256, 0, stream>>>(v_ws, vT_ws);

    flash_attn<<<dim3(8, 32), 512, 0, stream>>>(q_ws, k_ws, vT_ws, attn);

    QkvPtrs po;
    po.W[0] = wbo; po.W[1] = wbo; po.W[2] = wbo;
    po.out[0] = d_out; po.out[1] = d_out; po.out[2] = d_out;
    po.scale[0] = 1.0f; po.scale[1] = 1.0f; po.scale[2] = 1.0f;
    po.mode[0] = 1; po.mode[1] = 1; po.mode[2] = 1;
    gemm_bt<<<dim3(64, 5, 1), 256, 0, stream>>>(attn, po, bo);
}

// Round 12
// 192.165 us; speedup vs baseline: 2.3240x; 2.3240x over previous
//
#include <hip/hip_runtime.h>

typedef unsigned short u16;
typedef unsigned int u32;
typedef unsigned long long u64;

typedef __bf16 bf16x8 __attribute__((ext_vector_type(8)));
typedef float f32x4 __attribute__((ext_vector_type(4)));
typedef float f32x16 __attribute__((ext_vector_type(16)));

__device__ __forceinline__ float b2f(u16 u) {
    union { u32 i; float f; } c; c.i = ((u32)u) << 16; return c.f;
}
__device__ __forceinline__ u16 f2b(float f) {
    union { float f; u32 i; } c; c.f = f;
    u32 r = c.i + 0x7fffu + ((c.i >> 16) & 1u);
    return (u16)(r >> 16);
}
__device__ __forceinline__ u32 pack2(float a, float b) {
    return (u32)f2b(a) | ((u32)f2b(b) << 16);
}
// packed f32x2 -> bf16x2 in ONE instruction (gfx950)
__device__ __forceinline__ u32 cvt_pk_bf16(float a, float b) {
    u32 r;
    asm("v_cvt_pk_bf16_f32 %0, %1, %2" : "=v"(r) : "v"(a), "v"(b));
    return r;
}
__device__ __forceinline__ float fexp2(float x) {
    float r;
    asm("v_exp_f32 %0, %1" : "=v"(r) : "v"(x));
    return r;
}

__device__ __forceinline__ f32x4 mfma16(bf16x8 a, bf16x8 b, f32x4 c) {
    return __builtin_amdgcn_mfma_f32_16x16x32_bf16(a, b, c, 0, 0, 0);
}
__device__ __forceinline__ f32x16 mfma32(bf16x8 a, bf16x8 b, f32x16 c) {
    return __builtin_amdgcn_mfma_f32_32x32x16_bf16(a, b, c, 0, 0, 0);
}

__device__ __forceinline__ void lds_cp16(const u16* gsrc, u16* ldst) {
    __builtin_amdgcn_global_load_lds(
        (const __attribute__((address_space(1))) u32*)gsrc,
        (__attribute__((address_space(3))) u32*)ldst, 16, 0, 0);
}

// ---------------------------------------------------------------------------
// prep: (a) LoRA-FOLDED weight convert: Wb = bf16(W + up·down)  (fp32 fold,
//        single bf16 rounding — algebraic identity x@W.T + (x@dn.T)@up.T
//        == x@(W + up@dn).T), (b) xb = bf16(x), (c) V^T pad rows.
// flat grid: [0,1600) weights, [1600,2880) x convert, [2880,3904) pads.
// ---------------------------------------------------------------------------
struct ConvJobs {
    const float* s[4];    // wq, wk, wv, wo  [640][640]
    const float* up[4];   // q_up, ...       [640][4]
    const float* dn[4];   // q_down, ...     [4][640]
    u16* d[4];
};

__global__ __launch_bounds__(256) void prep(ConvJobs J,
                                            const float* __restrict__ x,
                                            u16* __restrict__ xb,
                                            u16* __restrict__ vt, int do_pad) {
    int bx = blockIdx.x;
    if (bx < 1600) {
        int j = bx / 400;
        int i = (bx - j * 400) * 256 + threadIdx.x;   // float4 idx < 102400
        int n = i / 160;                               // output row (0..639)
        int k4 = (i - n * 160) * 4;                    // col base
        float4 w = ((const float4*)J.s[j])[i];
        float4 u = *(const float4*)(J.up[j] + n * 4);
        const float* dnp = J.dn[j];
        float4 d0 = *(const float4*)(dnp + k4);
        float4 d1 = *(const float4*)(dnp + 640 + k4);
        float4 d2 = *(const float4*)(dnp + 1280 + k4);
        float4 d3 = *(const float4*)(dnp + 1920 + k4);
        ushort4 o;
        o.x = f2b(w.x + u.x * d0.x + u.y * d1.x + u.z * d2.x + u.w * d3.x);
        o.y = f2b(w.y + u.x * d0.y + u.y * d1.y + u.z * d2.y + u.w * d3.y);
        o.z = f2b(w.z + u.x * d0.z + u.y * d1.z + u.z * d2.z + u.w * d3.z);
        o.w = f2b(w.w + u.x * d0.w + u.y * d1.w + u.z * d2.w + u.w * d3.w);
        ((ushort4*)J.d[j])[i] = o;
    } else if (bx < 2880) {
        // x fp32 -> bf16: 8192*640 = 5,242,880 floats = 1280 blocks * 1024 f4
        int base = (bx - 1600) * 1024 + threadIdx.x;
#pragma unroll
        for (int it = 0; it < 4; ++it) {
            int i = base + it * 256;
            float4 v = ((const float4*)x)[i];
            ushort4 o;
            o.x = f2b(v.x); o.y = f2b(v.y); o.z = f2b(v.z); o.w = f2b(v.w);
            ((ushort4*)xb)[i] = o;
        }
    } else if (do_pad) {
        // 32 bh * 16 rows * 2048 cols u16, 4 u16/thread = 1024 blocks
        int idx = (bx - 2880) * 256 + threadIdx.x;
        int q = idx * 4;
        int bh = q >> 15;
        int rem = q & 32767;
        int row = rem >> 11, col = rem & 2047;
        u16 val = (row == 0) ? (u16)0x3F80 : (u16)0;
        ushort4 o = make_ushort4(val, val, val, val);
        *(ushort4*)(vt + ((size_t)bh * 96 + 80 + row) * 2048 + col) = o;
    }
}

// ---------------------------------------------------------------------------
// C[m][n] = sum_k A[m][k]*W[n][k]  (+bias[n] in mode 1) — LoRA pre-folded in W.
// PIPELINED K-loop (T3/T4): 3 LDS buffers, 2-deep prefetch, counted
// s_waitcnt vmcnt(4) + raw s_barrier (never vmcnt(0) in main loop).
// per-z mode: 0 = bf16 [B,H,S,hd] scaled          (Q,K; legacy V fallback)
//             1 = fp32 [M,640] + bias             (O-proj)
//             2 = V^T bf16 [B,H,96,S] key-permuted, via LDS-transposed
//                 epilogue with fully coalesced row stores
// ---------------------------------------------------------------------------
struct QkvPtrs {
    const u16* W[3];
    void* out[3];
    float scale[3];
    int mode[3];
};

__global__ __launch_bounds__(256) void gemm_bt(const u16* __restrict__ A, QkvPtrs P,
                                               const float* __restrict__ bias) {
    int z = blockIdx.z;
    const u16* W = P.W[z];
    const float scl = P.scale[z];
    const int md = P.mode[z];
    int m0 = blockIdx.x * 128, n0 = blockIdx.y * 128;
    int tid = threadIdx.x, lane = tid & 63, wid = tid >> 6;
    int g = lane >> 4, l15 = lane & 15;
    // 48 KB: As = smem[0..12288), Bs = smem[12288..24576); front 34816 B reused
    // as the 128x136 u16 transpose buffer in the mode-2 epilogue.
    __shared__ __align__(16) u16 smem[24576];
    u16* As_ = smem;
    u16* Bs_ = smem + 12288;
    f32x4 acc[4][4] = {};
    int wm = (wid & 1) * 64, wn = (wid >> 1) * 64;

    // per-thread staging: chunk tid -> row tid>>2 (of 64), col (tid&3)*8;
    // second lds_cp covers rows 64..127. LDS dest linear = wave-uniform+lane*16.
    int r0 = tid >> 2, cb = (tid & 3) * 8;
    const u16* pA = A + (size_t)(m0 + r0) * 640 + cb;
    const u16* pB = W + (size_t)(n0 + r0) * 640 + cb;

    auto stage = [&](int buf, int k0) {
        u16* da = As_ + buf * 4096 + tid * 8;
        u16* db = Bs_ + buf * 4096 + tid * 8;
        lds_cp16(pA + k0, da);
        lds_cp16(pA + 40960 + k0, da + 2048);   // +64 rows
        lds_cp16(pB + k0, db);
        lds_cp16(pB + 40960 + k0, db + 2048);
    };
    auto compute = [&](int cur) {
        const u16* as = As_ + cur * 4096;
        const u16* bs = Bs_ + cur * 4096;
        bf16x8 af[4], bfv[4];
#pragma unroll
        for (int q4 = 0; q4 < 4; ++q4) {
            af[q4]  = *(const bf16x8*)(as + (wm + q4 * 16 + l15) * 32 + g * 8);
            bfv[q4] = *(const bf16x8*)(bs + (wn + q4 * 16 + l15) * 32 + g * 8);
        }
#pragma unroll
        for (int i = 0; i < 4; ++i)
#pragma unroll
            for (int j = 0; j < 4; ++j)
                acc[i][j] = mfma16(af[i], bfv[j], acc[i][j]);
    };

    stage(0, 0);
    stage(1, 32);          // 8 loads/thread outstanding
    int cur = 0;
    for (int t = 0; t < 19; ++t) {
        // stage(t) complete; stage(t+1)'s 4 loads may remain in flight.
        asm volatile("s_waitcnt vmcnt(4)" ::: "memory");
        __builtin_amdgcn_s_barrier();
        asm volatile("" ::: "memory");
        if (t < 18) stage((cur == 0) ? 2 : cur - 1, (t + 2) * 32);  // buf (t+2)%3
        compute(cur);
        cur = (cur == 2) ? 0 : cur + 1;
    }
    asm volatile("s_waitcnt vmcnt(0)" ::: "memory");
    __builtin_amdgcn_s_barrier();
    asm volatile("" ::: "memory");
    compute(cur);

    float bv[4];
#pragma unroll
    for (int j = 0; j < 4; ++j) {
        int n = n0 + wn + j * 16 + l15;
        bv[j] = (md == 1) ? bias[n] : 0.f;
    }

    if (md == 2) {
        // ---- V^T epilogue: LDS transpose then coalesced row stores ----
        __syncthreads();   // all waves done reading As/Bs before reuse
        u16* Tl = smem;    // [128 n][136 m] u16
#pragma unroll
        for (int i = 0; i < 4; ++i) {
#pragma unroll
            for (int j = 0; j < 4; ++j) {
                uint2 pk;
                pk.x = pack2(acc[i][j][0], acc[i][j][1]);
                pk.y = pack2(acc[i][j][2], acc[i][j][3]);
                *(uint2*)(Tl + (wn + j * 16 + l15) * 136 + wm + i * 16 + g * 4) = pk;
            }
        }
        __syncthreads();
        int bb2 = m0 >> 11;
        int sl0 = m0 & 2047;               // s offset WITHIN batch
        u16* outb_ = (u16*)P.out[z];
#pragma unroll
        for (int it = 0; it < 16; ++it) {
            int qq = it * 256 + tid;        // 0..4095 quads
            int row = qq >> 5;              // n_local
            int pos = (qq & 31) * 4;        // output position (quad-aligned)
            // position p holds key perm(p): read source key-quad perm(pos)
            int ss = (pos & ~12) | ((pos & 4) << 1) | ((pos & 8) >> 1);
            uint2 val = *(const uint2*)(Tl + row * 136 + ss);
            int n = n0 + row;
            int h = n / 80, d = n - h * 80;
            *(uint2*)(outb_ + (((size_t)bb2 * 8 + h) * 96 + d) * 2048 + sl0 + pos) = val;
        }
        return;
    }

    float* outf = (float*)P.out[z];
    u16* outb = (u16*)P.out[z];
#pragma unroll
    for (int i = 0; i < 4; ++i) {
#pragma unroll
        for (int r = 0; r < 4; ++r) {
            int m = m0 + wm + i * 16 + g * 4 + r;
#pragma unroll
            for (int j = 0; j < 4; ++j) {
                int n = n0 + wn + j * 16 + l15;
                float v = acc[i][j][r] + bv[j];
                if (md == 1) {
                    outf[(size_t)m * 640 + n] = v;
                } else {
                    int bb = m >> 11, s = m & 2047;
                    int h = n / 80, d = n - h * 80;
                    outb[(((size_t)bb * 8 + h) * 2048 + s) * 80 + d] = f2b(v * scl);
                }
            }
        }
    }
}

// ---------------------------------------------------------------------------
// V transpose (LEGACY fallback when workspace too small for direct V^T):
// [B,H,S,80] -> [B,H,96,S] key-permuted, rows 80=ones, 81..95=0.
// ---------------------------------------------------------------------------
__global__ __launch_bounds__(256) void transpose_v(const u16* __restrict__ Vin,
                                                   u16* __restrict__ Vout) {
    __shared__ u32 lds32[64 * 41];
    int bh = blockIdx.y;
    int s0 = blockIdx.x * 64;
    int tid = threadIdx.x;
    const u16* in = Vin + (size_t)bh * 2048 * 80;
    u16* out = Vout + (size_t)bh * 96 * 2048;

    for (int t = tid; t < 640; t += 256) {
        int s = t / 10, c = t - s * 10;
        uint4 v = *(const uint4*)(in + (size_t)(s0 + s) * 80 + c * 8);
        u32* p = lds32 + s * 41 + c * 4;
        p[0] = v.x; p[1] = v.y; p[2] = v.z; p[3] = v.w;
    }
    __syncthreads();
    for (int t = tid; t < 640; t += 256) {
        int d = t >> 3, c8 = t & 7;
        int dp = d >> 1, hi = d & 1;
        u16 vals[8];
#pragma unroll
        for (int j = 0; j < 8; ++j) {
            u32 w = lds32[(c8 * 8 + j) * 41 + dp];
            vals[j] = hi ? (u16)(w >> 16) : (u16)(w & 0xffff);
        }
        u16* dst = out + (size_t)d * 2048 + s0 + (c8 >> 1) * 16 + (c8 & 1) * 4;
        *(uint2*)dst = *(const uint2*)(vals);
        *(uint2*)(dst + 8) = *(const uint2*)(vals + 4);
    }
    for (int t = tid; t < 1024; t += 256) {
        int r = t >> 6, c = t & 63;
        out[(size_t)(80 + r) * 2048 + s0 + c] = (r == 0) ? 0x3F80 : 0;
    }
}

// ---------------------------------------------------------------------------
// Flash attention v8 (R8/R10-proven): head-major Q,K [B,H,S,80];
// S^T MFMA, lane-local P (V key-permuted), exp2 direct (Q pre-scaled),
// cvt_pk packing, dbuf staging, 1 barrier/tile, setprio (T5).
// grid (8, 32), 512 threads. Vt_g: [B,H,96,S] (row 80 = ones -> l_i free).
// ---------------------------------------------------------------------------
__global__ __launch_bounds__(512) void flash_attn(const u16* __restrict__ Q,
                                                  const u16* __restrict__ K,
                                                  const u16* __restrict__ Vt_g,
                                                  u16* __restrict__ O) {
    int bh = blockIdx.y;
    int q0 = blockIdx.x * 256;
    int tid = threadIdx.x;
    int lane = tid & 63, wid = tid >> 6, l31 = lane & 31, h2 = lane >> 5;
    const size_t base = (size_t)bh * 2048 * 80;     // Q,K
    const size_t vbase = (size_t)bh * 96 * 2048;    // Vt_g

    __shared__ __align__(16) u16 lds[2 * 5632 + 2 * 7200];
    u16* Ks0 = lds;
    u16* Vt0 = lds + 11264;

    // Q fragments: B[n=l31 q][k=h2*8+j], 5 k-slices of 16
    bf16x8 qf[5];
    {
        int qrow = q0 + wid * 32 + l31;
#pragma unroll
        for (int ks = 0; ks < 5; ++ks)
            qf[ks] = *(const bf16x8*)(Q + base + (size_t)qrow * 80 + ks * 16 + h2 * 8);
    }

    f32x16 oa[3] = {};
    // Q pre-scaled by sm_scale*log2e; exp(s*sm - 12) == exp2(s' - 12*log2e)
    const float C2 = 17.312340490667562f;

    auto stage = [&](int buf, int kt) {
#pragma unroll
        for (int it = 0; it < 4; ++it) {
            int c = tid + it * 512;
            if (c < 704) {
                int row = c / 11, col = c - row * 11;
                lds_cp16(K + base + (size_t)(kt + row) * 80 + col * 8,
                         Ks0 + buf * 5632 + c * 8);
            } else if (c < 1600) {
                int t = c - 704;
                int row = t / 9, col = t - row * 9;
                lds_cp16(Vt_g + vbase + (size_t)row * 2048 + kt + col * 8,
                         Vt0 + buf * 7200 + t * 8);
            }
        }
    };

    stage(0, 0);
    __syncthreads();

    for (int i = 0; i < 32; ++i) {
        int cur = i & 1;
        if (i < 31) stage(cur ^ 1, (i + 1) * 64);

        const u16* ks = Ks0 + cur * 5632;
        const u16* vt = Vt0 + cur * 7200;

#pragma unroll
        for (int kk2 = 0; kk2 < 2; ++kk2) {
            // S^T = K*Q^T: lane -> q-col=l31, key-row=(reg&3)+8*(reg>>2)+4*h2+32*kk2
            f32x16 s = {};
            __builtin_amdgcn_s_setprio(1);
#pragma unroll
            for (int ks5 = 0; ks5 < 5; ++ks5) {
                bf16x8 kf = *(const bf16x8*)(ks + (kk2 * 32 + l31) * 88 + ks5 * 16 + h2 * 8);
                s = mfma32(kf, qf[ks5], s);
            }
            __builtin_amdgcn_s_setprio(0);
            // d[j] = keys 8*(j>>1) + 4*h2 + 2*(j&1) + {0,1} -- lane-local.
            // V is key-permuted so pa.w[j] = d[4*sl+j] directly (no shfl/cndmask).
            u32 d[8];
#pragma unroll
            for (int j = 0; j < 8; ++j)
                d[j] = cvt_pk_bf16(fexp2(s[2 * j] - C2), fexp2(s[2 * j + 1] - C2));
            __builtin_amdgcn_s_setprio(1);
#pragma unroll
            for (int sl = 0; sl < 2; ++sl) {
                union { u32 w[4]; bf16x8 v; } pa;
                pa.w[0] = d[4 * sl + 0];
                pa.w[1] = d[4 * sl + 1];
                pa.w[2] = d[4 * sl + 2];
                pa.w[3] = d[4 * sl + 3];
#pragma unroll
                for (int nt = 0; nt < 3; ++nt) {
                    bf16x8 vf = *(const bf16x8*)(vt + (nt * 32 + l31) * 72 +
                                                 kk2 * 32 + sl * 16 + h2 * 8);
                    oa[nt] = mfma32(pa.v, vf, oa[nt]);
                }
            }
            __builtin_amdgcn_s_setprio(0);
        }
        __syncthreads();
    }

    // epilogue: l_i lives in oa[2] col 16 (vd=80 ones column)
    int b = bh >> 3, h = bh & 7;
    float inv[16];
#pragma unroll
    for (int reg = 0; reg < 16; ++reg)
        inv[reg] = 1.f / __shfl(oa[2][reg], (lane & 32) + 16, 64);
#pragma unroll
    for (int nt = 0; nt < 3; ++nt) {
        int vd = nt * 32 + l31;
        if (vd < 80) {
#pragma unroll
            for (int reg = 0; reg < 16; ++reg) {
                int q = q0 + wid * 32 + (reg & 3) + 8 * (reg >> 2) + 4 * h2;
                O[((size_t)(b * 2048 + q)) * 640 + h * 80 + vd] = f2b(oa[nt][reg] * inv[reg]);
            }
        }
    }
}

// ---------------------------------------------------------------------------
extern "C" void kernel_launch(void* const* d_in, const int* in_sizes, int n_in,
                              void* d_out, int out_size, void* d_ws, size_t ws_size,
                              hipStream_t stream) {
    const float* x      = (const float*)d_in[0];
    const float* wq     = (const float*)d_in[1];
    const float* wk     = (const float*)d_in[2];
    const float* wv     = (const float*)d_in[3];
    const float* wo     = (const float*)d_in[4];
    const float* bo     = (const float*)d_in[5];
    const float* q_down = (const float*)d_in[6];
    const float* q_up   = (const float*)d_in[7];
    const float* k_down = (const float*)d_in[8];
    const float* k_up   = (const float*)d_in[9];
    const float* v_down = (const float*)d_in[10];
    const float* v_up   = (const float*)d_in[11];
    const float* o_down = (const float*)d_in[12];
    const float* o_up   = (const float*)d_in[13];

    char* ws = (char*)d_ws;
    u16* xb    = (u16*)(ws);                  // [8192][640] bf16 (dead after gemmQKV)
    u16* wbv   = (u16*)(ws + 10485760);
    u16* wbq   = (u16*)(ws + 11304960);
    u16* wbk   = (u16*)(ws + 12124160);
    u16* wbo   = (u16*)(ws + 12943360);
    u16* q_ws  = (u16*)(ws + 13762560);       // [B,H,S,80] bf16 (pre-scaled)
    u16* k_ws  = (u16*)(ws + 24248320);       // [B,H,S,80]
    u16* v_ws  = (u16*)(ws + 34734080);       // [B,H,S,80] natural (legacy only)
    u16* attn  = (u16*)(ws + 45219840);       // [B*S][640] bf16, ends 55705600

    // V^T [B,H,96,S] = 12,582,912 B at its own region past the watermark
    // (+16KB slack: flash stages up to ~8KB past the logical end, reads only).
    const size_t vt_off = 56360960;
    const size_t vt_need = vt_off + 12582912 + 16384;
    const bool direct_vt = (ws_size >= vt_need);
    u16* vT_ws = direct_vt ? (u16*)(ws + vt_off)
                           : (u16*)(ws);      // legacy: overlaps xb (dead by then)

    // 0) LoRA-folded weight convert + x convert + V^T pads (one kernel)
    ConvJobs cj;
    cj.s[0] = wq; cj.up[0] = q_up; cj.dn[0] = q_down; cj.d[0] = wbq;
    cj.s[1] = wk; cj.up[1] = k_up; cj.dn[1] = k_down; cj.d[1] = wbk;
    cj.s[2] = wv; cj.up[2] = v_up; cj.dn[2] = v_down; cj.d[2] = wbv;
    cj.s[3] = wo; cj.up[3] = o_up; cj.dn[3] = o_down; cj.d[3] = wbo;
    prep<<<3904, 256, 0, stream>>>(cj, x, xb, vT_ws, direct_vt ? 1 : 0);

    // 1) QKV projections (LoRA folded); Q pre-scaled by sm*log2e; V direct-V^T
    QkvPtrs pq;
    pq.W[0] = wbq; pq.W[1] = wbk; pq.W[2] = wbv;
    pq.out[0] = q_ws; pq.out[1] = k_ws;
    pq.out[2] = direct_vt ? (void*)vT_ws : (void*)v_ws;
    pq.scale[0] = 0.11180339887498949f * 1.4426950408889634f;  // 1/sqrt(80)*log2e
    pq.scale[1] = 1.0f;
    pq.scale[2] = 1.0f;
    pq.mode[0] = 0; pq.mode[1] = 0; pq.mode[2] = direct_vt ? 2 : 0;
    gemm_bt<<<dim3(64, 5, 3), 256, 0, stream>>>(xb, pq, bo);

    // 2) legacy fallback: separate V transpose pass
    if (!direct_vt)
        transpose_v<<<dim3(32, 32), 256, 0, stream>>>(v_ws, vT_ws);

    // 3) attention (dbuf, 1 barrier/tile, setprio) -> token-major bf16
    flash_attn<<<dim3(8, 32), 512, 0, stream>>>(q_ws, k_ws, vT_ws, attn);

    // 4) O projection (LoRA folded, +bias) -> fp32 d_out
    QkvPtrs po;
    po.W[0] = wbo; po.W[1] = wbo; po.W[2] = wbo;
    po.out[0] = d_out; po.out[1] = d_out; po.out[2] = d_out;
    po.scale[0] = 1.0f; po.scale[1] = 1.0f; po.scale[2] = 1.0f;
    po.mode[0] = 1; po.mode[1] = 1; po.mode[2] = 1;
    gemm_bt<<<dim3(64, 5, 1), 256, 0, stream>>>(attn, po, bo);
}